// Round 11
// baseline (3346.593 us; speedup 1.0000x reference)
//
#include <hip/hip_runtime.h>
#include <cstddef>

#define D_    128
#define NV_   65536
#define NL_   131072
#define NC_   262144
#define NE_   1048576
#define NROUNDS_ 8

typedef __attribute__((ext_vector_type(4)))  short short4v;
typedef __attribute__((ext_vector_type(8)))  short short8v;   // 8 bf16 = 4 VGPRs (MFMA A/B frag)
typedef __attribute__((ext_vector_type(16))) float f32x16;    // MFMA 32x32 C/D frag

// ---------------- fp32 helpers ----------------
__device__ __forceinline__ float4 f4_load(const float* p) { return *(const float4*)p; }
__device__ __forceinline__ void   f4_store(float* p, float4 v) { *(float4*)p = v; }
__device__ __forceinline__ float4 f4_zero() { return make_float4(0.f, 0.f, 0.f, 0.f); }
__device__ __forceinline__ float4 f4_add(float4 a, float4 b) {
    a.x += b.x; a.y += b.y; a.z += b.z; a.w += b.w; return a;
}
__device__ __forceinline__ float4 f4_scale(float4 a, float s) {
    a.x *= s; a.y *= s; a.z *= s; a.w *= s; return a;
}
// Non-temporal float4 load (state stream: keep gather tables L3-resident).
__device__ __forceinline__ float4 f4_load_nt(const float* p) {
    float x = __builtin_nontemporal_load(p);
    float y = __builtin_nontemporal_load(p + 1);
    float z = __builtin_nontemporal_load(p + 2);
    float w = __builtin_nontemporal_load(p + 3);
    return make_float4(x, y, z, w);
}

__device__ __forceinline__ void micro_fma(const float4 a[4], const float4 w[4], float4 acc[4]) {
#pragma unroll
    for (int i = 0; i < 4; i++) {
        float4 av = a[i];
        acc[i].x += av.x * w[0].x; acc[i].x += av.y * w[1].x; acc[i].x += av.z * w[2].x; acc[i].x += av.w * w[3].x;
        acc[i].y += av.x * w[0].y; acc[i].y += av.y * w[1].y; acc[i].y += av.z * w[2].y; acc[i].y += av.w * w[3].y;
        acc[i].z += av.x * w[0].z; acc[i].z += av.y * w[1].z; acc[i].z += av.z * w[2].z; acc[i].z += av.w * w[3].z;
        acc[i].w += av.x * w[0].w; acc[i].w += av.y * w[1].w; acc[i].w += av.z * w[2].w; acc[i].w += av.w * w[3].w;
    }
}

template<int KD, bool FLIP>
__device__ __forceinline__ void layer1_to_H(float* Xs, float* Wcs,
        const float* __restrict__ W1, const float* __restrict__ b1, int t)
{
    const int tr = t >> 5, tc = t & 31;
    float4 acc[4];
    acc[0] = acc[1] = acc[2] = acc[3] = f4_zero();
#pragma unroll 1
    for (int kc = 0; kc < KD; kc += 32) {
        __syncthreads();
#pragma unroll
        for (int i = t; i < 1024; i += 256)
            ((float4*)Wcs)[i] = ((const float4*)W1)[kc * 32 + i];
        __syncthreads();
        const bool fl = FLIP && (kc >= 256);
        const int ab = fl ? (kc - 256) : kc;
#pragma unroll
        for (int k = 0; k < 32; k += 4) {
            float4 a[4], w[4];
#pragma unroll
            for (int i = 0; i < 4; i++) {
                int r = 4 * tr + i;
                if (fl) r ^= 1;
                a[i] = f4_load(Xs + r * 256 + ab + k);
            }
#pragma unroll
            for (int kk = 0; kk < 4; kk++)
                w[kk] = f4_load(Wcs + (k + kk) * 128 + 4 * tc);
            micro_fma(a, w, acc);
        }
    }
    float4 bv = f4_load(b1 + 4 * tc);
    __syncthreads();
#pragma unroll
    for (int i = 0; i < 4; i++) {
        float4 h;
        h.x = fmaxf(acc[i].x + bv.x, 0.f);
        h.y = fmaxf(acc[i].y + bv.y, 0.f);
        h.z = fmaxf(acc[i].z + bv.z, 0.f);
        h.w = fmaxf(acc[i].w + bv.w, 0.f);
        f4_store(Xs + (4 * tr + i) * 256 + 128 + 4 * tc, h);
    }
}

// ---------------- bf16 split helpers ----------------
__device__ __forceinline__ unsigned short f2bf(float x) {
    unsigned u = __float_as_uint(x);
    u += 0x7fffu + ((u >> 16) & 1u);           // RNE
    return (unsigned short)(u >> 16);
}
__device__ __forceinline__ float bf2f(unsigned short h) {
    return __uint_as_float(((unsigned)h) << 16);
}
__device__ __forceinline__ void split_bf(float x, unsigned short& h, unsigned short& l) {
    h = f2bf(x);
    l = f2bf(x - bf2f(h));
}
__device__ __forceinline__ void cvt4(const float4& a, short4v& h, short4v& l) {
    unsigned short h0,h1,h2,h3,l0,l1,l2,l3;
    split_bf(a.x,h0,l0); split_bf(a.y,h1,l1); split_bf(a.z,h2,l2); split_bf(a.w,h3,l3);
    h = (short4v){(short)h0,(short)h1,(short)h2,(short)h3};
    l = (short4v){(short)l0,(short)l1,(short)l2,(short)l3};
}
__device__ __forceinline__ void cvt8(const float4& a, const float4& b, short8v& h, short8v& l) {
    unsigned short h0,h1,h2,h3,h4,h5,h6,h7,l0,l1,l2,l3,l4,l5,l6,l7;
    split_bf(a.x,h0,l0); split_bf(a.y,h1,l1); split_bf(a.z,h2,l2); split_bf(a.w,h3,l3);
    split_bf(b.x,h4,l4); split_bf(b.y,h5,l5); split_bf(b.z,h6,l6); split_bf(b.w,h7,l7);
    h = (short8v){(short)h0,(short)h1,(short)h2,(short)h3,(short)h4,(short)h5,(short)h6,(short)h7};
    l = (short8v){(short)l0,(short)l1,(short)l2,(short)l3,(short)l4,(short)l5,(short)l6,(short)l7};
}

// Plane swizzle: [32][128] bf16, row stride 256 B, XOR bit4..6 by row&7
__device__ __forceinline__ int pswz(int r, int k) { return (r * 256 + k * 2) ^ ((r & 7) << 4); }

// ---------------- weight packing ----------------
__global__ void pack_weights(const float* __restrict__ W, short* __restrict__ out, int K)
{
    int o = blockIdx.x * 256 + threadIdx.x;
    if (o >= 2 * K * 128) return;
    int i = o & 7;
    int g = o >> 3;
    int n  = g & 127;
    int kk = (g >> 7) & 3;
    int p  = (g >> 9) & 1;
    int c  = g >> 10;
    int k  = c * 32 + kk * 8 + i;
    float x = W[k * 128 + n];
    unsigned short h = f2bf(x);
    unsigned short v = p ? f2bf(x - bf2f(h)) : h;
    out[o] = (short)v;
}

// ---------------- setup kernels ----------------
__global__ void fill_kernel(float* __restrict__ L, float* __restrict__ C,
                            const float* __restrict__ lsp, const float* __restrict__ csp)
{
    const float ls = *lsp, cs = *csp;
    const size_t stride = (size_t)gridDim.x * blockDim.x;
    size_t i0 = (size_t)blockIdx.x * blockDim.x + threadIdx.x;
    const size_t nL = (size_t)NL_ * D_ / 4, nC = (size_t)NC_ * D_ / 4;
    float4 lv = make_float4(ls, ls, ls, ls), cv = make_float4(cs, cs, cs, cs);
    for (size_t i = i0; i < nL; i += stride) ((float4*)L)[i] = lv;
    for (size_t i = i0; i < nC; i += stride) ((float4*)C)[i] = cv;
}

__global__ void count_kernel(const int* __restrict__ ci, const int* __restrict__ li,
                             int* __restrict__ ccnt, int* __restrict__ lcnt)
{
    int e = blockIdx.x * 256 + threadIdx.x;
    if (e < NE_) {
        atomicAdd(&ccnt[ci[e]], 1);
        atomicAdd(&lcnt[li[e]], 1);
    }
}

__global__ void scan_block(const int* __restrict__ in, int* __restrict__ out,
                           int* __restrict__ bsum)
{
    __shared__ int sh[256];
    const int t = threadIdx.x;
    const int base = blockIdx.x * 1024 + t * 4;
    int v0 = in[base], v1 = in[base + 1], v2 = in[base + 2], v3 = in[base + 3];
    int s = v0 + v1 + v2 + v3;
    sh[t] = s;
    __syncthreads();
    for (int off = 1; off < 256; off <<= 1) {
        int y = (t >= off) ? sh[t - off] : 0;
        __syncthreads();
        sh[t] += y;
        __syncthreads();
    }
    int excl = sh[t] - s;
    out[base + 0] = excl;
    out[base + 1] = excl + v0;
    out[base + 2] = excl + v0 + v1;
    out[base + 3] = excl + v0 + v1 + v2;
    if (t == 255) bsum[blockIdx.x] = sh[255];
}

__global__ void scan_top(int* __restrict__ bs, int n)
{
    __shared__ int sh[256];
    const int t = threadIdx.x;
    int v = (t < n) ? bs[t] : 0;
    sh[t] = v;
    __syncthreads();
    for (int off = 1; off < 256; off <<= 1) {
        int y = (t >= off) ? sh[t - off] : 0;
        __syncthreads();
        sh[t] += y;
        __syncthreads();
    }
    if (t < n) bs[t] = sh[t] - v;
}

__global__ void scan_add(int* __restrict__ offs, const int* __restrict__ bs,
                         int* __restrict__ cur, int n, int total)
{
    int i = blockIdx.x * 256 + threadIdx.x;
    if (i < n) {
        int v = offs[i] + bs[i >> 10];
        offs[i] = v;
        cur[i] = v;
    }
    if (i == 0) offs[n] = total;
}

__global__ void fill_csr(const int* __restrict__ ci, const int* __restrict__ li,
                         int* __restrict__ ccur, int* __restrict__ lcur,
                         int* __restrict__ cedges, int* __restrict__ ledges)
{
    int e = blockIdx.x * 256 + threadIdx.x;
    if (e < NE_) {
        int c = ci[e], l = li[e];
        int p = atomicAdd(&ccur[c], 1); cedges[p] = l;
        int q = atomicAdd(&lcur[l], 1); ledges[q] = c;
    }
}

// ---------------- fused update kernel ----------------------------------------------
// Round-8 structure + (a) named-register preload of the first B-fragments so their
// L2 latency hides under the gather/staging/H phases, (b) s_setprio around MFMA runs.
// All preload slots are distinct named variables (no arrays / ternary lvalues) to
// avoid the round-7 scratch demotion. Spill sentinel: WRITE_SIZE must stay 131072.
template<bool FLIP>
__global__ __launch_bounds__(256, 5) void update_mfma(
        float* __restrict__ Mat, const float* __restrict__ Src,
        const int* __restrict__ offs, const int* __restrict__ eidx,
        const short* __restrict__ Wp1, const float* __restrict__ b1,
        const short* __restrict__ Wp2, const float* __restrict__ b2,
        const float* __restrict__ scale_p)
{
    __shared__ __align__(16) unsigned char SM[32768];
    unsigned char* sm = SM;
    const int t = threadIdx.x;
    const int base = blockIdx.x * 32;
    const int lane = t & 63, w = t >> 6;
    const int rA = lane & 31;          // A row / D col-in-tile
    const int kg = lane >> 5;          // k-octet group
    const int nB = w * 32 + rA;        // global output col for B frag / bias / D

#define LOADBV(Wp, st, BH, BL) do {                                             \
        const short* Wc_ = (Wp) + ((st) >> 1) * 8192;                           \
        const int kk_ = ((st) & 1) * 2 + kg;                                    \
        BH = *(const short8v*)(Wc_ + ((size_t)(kk_ * 128 + nB)) * 8);           \
        BL = *(const short8v*)(Wc_ + ((size_t)((4 + kk_) * 128 + nB)) * 8);     \
    } while (0)

    // ---- preload L1 B-frags steps 0-1 (independent of everything; L2 latency
    //      hides under the whole gather+staging phase)
    short8v w0h, w0l, w1h, w1l;
    LOADBV(Wp1, 0, w0h, w0l);
    LOADBV(Wp1, 1, w1h, w1l);

    // ---- issue state loads (nt; arrive while gather chain runs)
    float4 sv[4];
#pragma unroll
    for (int j = 0; j < 4; ++j)
        sv[j] = f4_load_nt((const float*)(((const float4*)Mat) + (size_t)base * 32 + t + j * 256));

    // ---- gather messages (longest dependency chain), 2-edge unroll
    float4 a0 = f4_zero(), a1 = f4_zero(), a2 = f4_zero(), a3 = f4_zero();
    const int gr = t >> 3, gs = t & 7;
    {
        const int row = base + gr;
        const int e0 = offs[row], e1 = offs[row + 1];
        int e = e0;
        for (; e + 1 < e1; e += 2) {
            const float* P = Src + (size_t)eidx[e] * 128 + gs * 16;
            const float* Q = Src + (size_t)eidx[e + 1] * 128 + gs * 16;
            float4 p0 = f4_load(P), p1 = f4_load(P + 4), p2 = f4_load(P + 8), p3 = f4_load(P + 12);
            float4 q0 = f4_load(Q), q1 = f4_load(Q + 4), q2 = f4_load(Q + 8), q3 = f4_load(Q + 12);
            a0 = f4_add(a0, p0); a1 = f4_add(a1, p1); a2 = f4_add(a2, p2); a3 = f4_add(a3, p3);
            a0 = f4_add(a0, q0); a1 = f4_add(a1, q1); a2 = f4_add(a2, q2); a3 = f4_add(a3, q3);
        }
        if (e < e1) {
            const float* P = Src + (size_t)eidx[e] * 128 + gs * 16;
            a0 = f4_add(a0, f4_load(P));
            a1 = f4_add(a1, f4_load(P + 4));
            a2 = f4_add(a2, f4_load(P + 8));
            a3 = f4_add(a3, f4_load(P + 12));
        }
    }

    // ---- preload L1 steps 2-3 (overlap the conversion VALU below)
    short8v w2h, w2l, w3h, w3l;
    LOADBV(Wp1, 2, w2h, w2l);
    LOADBV(Wp1, 3, w3h, w3l);

    // ---- store state -> PlaneS
#pragma unroll
    for (int j = 0; j < 4; ++j) {
        int i = t + j * 256;
        int r = i >> 5, q = i & 31;
        short4v hv, lv;
        cvt4(sv[j], hv, lv);
        *(short4v*)(sm + pswz(r, 4 * q)) = hv;
        *(short4v*)(sm + 8192 + pswz(r, 4 * q)) = lv;
    }
    // ---- store msgs -> PlaneM
    {
        const float sc = *scale_p;
        a0 = f4_scale(a0, sc); a1 = f4_scale(a1, sc);
        a2 = f4_scale(a2, sc); a3 = f4_scale(a3, sc);
        short8v mh0, ml0, mh1, ml1;
        cvt8(a0, a1, mh0, ml0);
        cvt8(a2, a3, mh1, ml1);
        const int k0 = 16 * gs;
        *(short8v*)(sm + 16384 + pswz(gr, k0))     = mh0;
        *(short8v*)(sm + 16384 + pswz(gr, k0 + 8)) = mh1;
        *(short8v*)(sm + 24576 + pswz(gr, k0))     = ml0;
        *(short8v*)(sm + 24576 + pswz(gr, k0 + 8)) = ml1;
    }
    __syncthreads();   // B1: PlaneS + PlaneM ready

    f32x16 c0, c1;
#pragma unroll
    for (int i = 0; i < 16; ++i) { c0[i] = 0.f; c1[i] = 0.f; }

    // MFMA step with preloaded B-frags (state cols, PlaneS)
#define MFMA_PRE(st, BH, BL) do {                                                   \
        short8v ah = *(const short8v*)(sm + pswz(rA, (st) * 16 + kg * 8));          \
        short8v al = *(const short8v*)(sm + 8192 + pswz(rA, (st) * 16 + kg * 8));   \
        c0 = __builtin_amdgcn_mfma_f32_32x32x16_bf16(ah, BH, c0, 0, 0, 0);          \
        c1 = __builtin_amdgcn_mfma_f32_32x32x16_bf16(ah, BL, c1, 0, 0, 0);          \
        c1 = __builtin_amdgcn_mfma_f32_32x32x16_bf16(al, BH, c1, 0, 0, 0);          \
    } while (0)

#define MFMA_STEP(Wp, st, ka, ar, AB) do {                                          \
        short8v ah = *(const short8v*)(sm + (AB) + pswz((ar), (ka)));               \
        short8v al = *(const short8v*)(sm + (AB) + 8192 + pswz((ar), (ka)));        \
        const short* Wc = (Wp) + ((st) >> 1) * 8192;                                \
        const int kk = ((st) & 1) * 2 + kg;                                         \
        short8v bh = *(const short8v*)(Wc + ((size_t)(kk * 128 + nB)) * 8);         \
        short8v bl = *(const short8v*)(Wc + ((size_t)((4 + kk) * 128 + nB)) * 8);   \
        c0 = __builtin_amdgcn_mfma_f32_32x32x16_bf16(ah, bh, c0, 0, 0, 0);          \
        c1 = __builtin_amdgcn_mfma_f32_32x32x16_bf16(ah, bl, c1, 0, 0, 0);          \
        c1 = __builtin_amdgcn_mfma_f32_32x32x16_bf16(al, bh, c1, 0, 0, 0);          \
    } while (0)

    __builtin_amdgcn_s_setprio(1);
    // ---- layer 1: steps 0-3 from preloads, 4-15 (+16-23 flip) inline
    MFMA_PRE(0, w0h, w0l);
    MFMA_PRE(1, w1h, w1l);
    MFMA_PRE(2, w2h, w2l);
    MFMA_PRE(3, w3h, w3l);
#pragma unroll 2
    for (int st = 4; st < 8; ++st)
        MFMA_STEP(Wp1, st, st * 16 + kg * 8, rA, 0);           // state cols (PlaneS)
#pragma unroll 2
    for (int st = 8; st < 16; ++st)
        MFMA_STEP(Wp1, st, (st - 8) * 16 + kg * 8, rA, 16384); // msg cols (PlaneM)
    if (FLIP) {
#pragma unroll 2
        for (int st = 16; st < 24; ++st)
            MFMA_STEP(Wp1, st, (st - 16) * 16 + kg * 8, rA ^ 1, 0); // flip: PlaneS, paired row
    }
    __builtin_amdgcn_s_setprio(0);
    __syncthreads();   // B2: all PlaneM (msg) reads done -> safe to overwrite with H

    // ---- preload L2 steps 0-1 (overlap H compute/store + barrier)
    LOADBV(Wp2, 0, w0h, w0l);
    LOADBV(Wp2, 1, w1h, w1l);

    // ---- H = relu(acc + b1) -> PlaneM (hi/lo)
    {
        const float b = b1[nB];
#pragma unroll
        for (int i = 0; i < 16; ++i) {
            int row = (i & 3) + 8 * (i >> 2) + 4 * kg;
            float h = fmaxf(c0[i] + c1[i] + b, 0.f);
            unsigned short hh, hl;
            split_bf(h, hh, hl);
            *(short*)(sm + 16384 + pswz(row, nB)) = (short)hh;
            *(short*)(sm + 24576 + pswz(row, nB)) = (short)hl;
        }
    }
    __syncthreads();   // B3: H visible

    // ---- residual from PlaneS (hi+lo ~= fp32); hidden under layer-2 MFMA
    float res[16];
#pragma unroll
    for (int i = 0; i < 16; ++i) {
        int row = (i & 3) + 8 * (i >> 2) + 4 * kg;
        unsigned short sh = *(const unsigned short*)(sm + pswz(row, nB));
        unsigned short sl = *(const unsigned short*)(sm + 8192 + pswz(row, nB));
        res[i] = bf2f(sh) + bf2f(sl);
    }

    // ---- layer 2: K=128 from PlaneM (H); steps 0-1 preloaded
#pragma unroll
    for (int i = 0; i < 16; ++i) { c0[i] = 0.f; c1[i] = 0.f; }
    __builtin_amdgcn_s_setprio(1);
    {
        short8v ah = *(const short8v*)(sm + 16384 + pswz(rA, kg * 8));
        short8v al = *(const short8v*)(sm + 24576 + pswz(rA, kg * 8));
        c0 = __builtin_amdgcn_mfma_f32_32x32x16_bf16(ah, w0h, c0, 0, 0, 0);
        c1 = __builtin_amdgcn_mfma_f32_32x32x16_bf16(ah, w0l, c1, 0, 0, 0);
        c1 = __builtin_amdgcn_mfma_f32_32x32x16_bf16(al, w0h, c1, 0, 0, 0);
        ah = *(const short8v*)(sm + 16384 + pswz(rA, 16 + kg * 8));
        al = *(const short8v*)(sm + 24576 + pswz(rA, 16 + kg * 8));
        c0 = __builtin_amdgcn_mfma_f32_32x32x16_bf16(ah, w1h, c0, 0, 0, 0);
        c1 = __builtin_amdgcn_mfma_f32_32x32x16_bf16(ah, w1l, c1, 0, 0, 0);
        c1 = __builtin_amdgcn_mfma_f32_32x32x16_bf16(al, w1h, c1, 0, 0, 0);
    }
#pragma unroll 2
    for (int st = 2; st < 8; ++st)
        MFMA_STEP(Wp2, st, st * 16 + kg * 8, rA, 16384);
    __builtin_amdgcn_s_setprio(0);
#undef MFMA_STEP
#undef MFMA_PRE
#undef LOADBV

    // ---- epilogue: out = acc + b2 + residual (nt store, write-only)
    {
        const float b = b2[nB];
#pragma unroll
        for (int i = 0; i < 16; ++i) {
            int row = (i & 3) + 8 * (i >> 2) + 4 * kg;
            size_t gi = (size_t)(base + row) * 128 + nB;
            __builtin_nontemporal_store(c0[i] + c1[i] + b + res[i], &Mat[gi]);
        }
    }
}

// ---------------- V scores (fp32 vector path, one small dispatch) ----------------
__global__ __launch_bounds__(256) void v_score(
        float* __restrict__ out, const float* __restrict__ Lmat,
        const float* __restrict__ W1, const float* __restrict__ b1,
        const float* __restrict__ W2, const float* __restrict__ b2)
{
    __shared__ float Xs[32 * 256];
    __shared__ float Wcs[32 * 128];
    const int t = threadIdx.x;
    const int base = blockIdx.x * 32;

#pragma unroll
    for (int i = t; i < 2048; i += 256)
        ((float4*)Xs)[i] = ((const float4*)Lmat)[(size_t)base * 64 + i];

    layer1_to_H<256, false>(Xs, Wcs, W1, b1, t);
    __syncthreads();
    if (t < 32) ((float4*)Wcs)[t] = ((const float4*)W2)[t];
    __syncthreads();

    const int r = t >> 3, s = t & 7;
    float sum = 0.f;
#pragma unroll
    for (int j = 0; j < 16; j++)
        sum += Xs[r * 256 + 128 + s * 16 + j] * Wcs[s * 16 + j];
    sum += __shfl_xor(sum, 1);
    sum += __shfl_xor(sum, 2);
    sum += __shfl_xor(sum, 4);
    if (s == 0) out[base + r] = sum + b2[0];
}

// ---------------- launch ----------------
extern "C" void kernel_launch(void* const* d_in, const int* in_sizes, int n_in,
                              void* d_out, int out_size, void* d_ws, size_t ws_size,
                              hipStream_t stream)
{
    const int*   ci   = (const int*)d_in[2];
    const int*   li   = (const int*)d_in[3];
    const float* Lsc  = (const float*)d_in[4];
    const float* Csc  = (const float*)d_in[5];
    const float* LCsc = (const float*)d_in[6];
    const float* CLsc = (const float*)d_in[7];
    const float* C_W1 = (const float*)d_in[8];
    const float* C_b1 = (const float*)d_in[9];
    const float* C_W2 = (const float*)d_in[10];
    const float* C_b2 = (const float*)d_in[11];
    const float* L_W1 = (const float*)d_in[12];
    const float* L_b1 = (const float*)d_in[13];
    const float* L_W2 = (const float*)d_in[14];
    const float* L_b2 = (const float*)d_in[15];
    const float* V_W1 = (const float*)d_in[16];
    const float* V_b1 = (const float*)d_in[17];
    const float* V_W2 = (const float*)d_in[18];
    const float* V_b2 = (const float*)d_in[19];
    float* out = (float*)d_out;

    // workspace carve
    char* w = (char*)d_ws;
    float* Cmat  = (float*)w; w += (size_t)NC_ * D_ * 4;        // 128 MB
    float* Lmat  = (float*)w; w += (size_t)NL_ * D_ * 4;        //  64 MB
    int* coffs   = (int*)w;   w += (size_t)(NC_ + 1) * 4;
    int* ccur    = (int*)w;   w += (size_t)NC_ * 4;
    int* cedges  = (int*)w;   w += (size_t)NE_ * 4;
    int* loffs   = (int*)w;   w += (size_t)(NL_ + 1) * 4;
    int* lcur    = (int*)w;   w += (size_t)NL_ * 4;
    int* ledges  = (int*)w;   w += (size_t)NE_ * 4;
    int* bsumC   = (int*)w;   w += 256 * 4;
    int* bsumL   = (int*)w;   w += 256 * 4;
    short* WpC1  = (short*)w; w += (size_t)2 * 256 * 128 * 2;   // packed hi/lo planes
    short* WpC2  = (short*)w; w += (size_t)2 * 128 * 128 * 2;
    short* WpL1  = (short*)w; w += (size_t)2 * 384 * 128 * 2;
    short* WpL2  = (short*)w; w += (size_t)2 * 128 * 128 * 2;

    hipMemsetAsync(ccur, 0, (size_t)NC_ * 4, stream);
    hipMemsetAsync(lcur, 0, (size_t)NL_ * 4, stream);

    pack_weights<<<(2 * 256 * 128) / 256, 256, 0, stream>>>(C_W1, WpC1, 256);
    pack_weights<<<(2 * 128 * 128) / 256, 256, 0, stream>>>(C_W2, WpC2, 128);
    pack_weights<<<(2 * 384 * 128) / 256, 256, 0, stream>>>(L_W1, WpL1, 384);
    pack_weights<<<(2 * 128 * 128) / 256, 256, 0, stream>>>(L_W2, WpL2, 128);

    fill_kernel<<<2048, 256, 0, stream>>>(Lmat, Cmat, Lsc, Csc);
    count_kernel<<<NE_ / 256, 256, 0, stream>>>(ci, li, ccur, lcur);

    scan_block<<<NC_ / 1024, 256, 0, stream>>>(ccur, coffs, bsumC);
    scan_top<<<1, 256, 0, stream>>>(bsumC, NC_ / 1024);
    scan_add<<<NC_ / 256, 256, 0, stream>>>(coffs, bsumC, ccur, NC_, NE_);

    scan_block<<<NL_ / 1024, 256, 0, stream>>>(lcur, loffs, bsumL);
    scan_top<<<1, 256, 0, stream>>>(bsumL, NL_ / 1024);
    scan_add<<<NL_ / 256, 256, 0, stream>>>(loffs, bsumL, lcur, NL_, NE_);

    fill_csr<<<NE_ / 256, 256, 0, stream>>>(ci, li, ccur, lcur, cedges, ledges);

    for (int r = 0; r < NROUNDS_; r++) {
        update_mfma<false><<<NC_ / 32, 256, 0, stream>>>(
            Cmat, Lmat, coffs, cedges, WpC1, C_b1, WpC2, C_b2, LCsc);
        update_mfma<true><<<NL_ / 32, 256, 0, stream>>>(
            Lmat, Cmat, loffs, ledges, WpL1, L_b1, WpL2, L_b2, CLsc);
    }
    v_score<<<NV_ / 32, 256, 0, stream>>>(out, Lmat, V_W1, V_b1, V_W2, V_b2);
}

// Round 12
// 2850.400 us; speedup vs baseline: 1.1741x; 1.1741x over previous
//
#include <hip/hip_runtime.h>
#include <cstddef>

#define D_    128
#define NV_   65536
#define NL_   131072
#define NC_   262144
#define NE_   1048576
#define NROUNDS_ 8

typedef __attribute__((ext_vector_type(4)))  short short4v;
typedef __attribute__((ext_vector_type(8)))  short short8v;   // 8 bf16 = 4 VGPRs (MFMA A/B frag)
typedef __attribute__((ext_vector_type(16))) float f32x16;    // MFMA 32x32 C/D frag

// ---------------- fp32 helpers ----------------
__device__ __forceinline__ float4 f4_load(const float* p) { return *(const float4*)p; }
__device__ __forceinline__ void   f4_store(float* p, float4 v) { *(float4*)p = v; }
__device__ __forceinline__ float4 f4_zero() { return make_float4(0.f, 0.f, 0.f, 0.f); }
__device__ __forceinline__ float4 f4_add(float4 a, float4 b) {
    a.x += b.x; a.y += b.y; a.z += b.z; a.w += b.w; return a;
}
__device__ __forceinline__ float4 f4_scale(float4 a, float s) {
    a.x *= s; a.y *= s; a.z *= s; a.w *= s; return a;
}
// Non-temporal float4 load (state stream: keep gather tables L3-resident).
__device__ __forceinline__ float4 f4_load_nt(const float* p) {
    float x = __builtin_nontemporal_load(p);
    float y = __builtin_nontemporal_load(p + 1);
    float z = __builtin_nontemporal_load(p + 2);
    float w = __builtin_nontemporal_load(p + 3);
    return make_float4(x, y, z, w);
}

__device__ __forceinline__ void micro_fma(const float4 a[4], const float4 w[4], float4 acc[4]) {
#pragma unroll
    for (int i = 0; i < 4; i++) {
        float4 av = a[i];
        acc[i].x += av.x * w[0].x; acc[i].x += av.y * w[1].x; acc[i].x += av.z * w[2].x; acc[i].x += av.w * w[3].x;
        acc[i].y += av.x * w[0].y; acc[i].y += av.y * w[1].y; acc[i].y += av.z * w[2].y; acc[i].y += av.w * w[3].y;
        acc[i].z += av.x * w[0].z; acc[i].z += av.y * w[1].z; acc[i].z += av.z * w[2].z; acc[i].z += av.w * w[3].z;
        acc[i].w += av.x * w[0].w; acc[i].w += av.y * w[1].w; acc[i].w += av.z * w[2].w; acc[i].w += av.w * w[3].w;
    }
}

template<int KD, bool FLIP>
__device__ __forceinline__ void layer1_to_H(float* Xs, float* Wcs,
        const float* __restrict__ W1, const float* __restrict__ b1, int t)
{
    const int tr = t >> 5, tc = t & 31;
    float4 acc[4];
    acc[0] = acc[1] = acc[2] = acc[3] = f4_zero();
#pragma unroll 1
    for (int kc = 0; kc < KD; kc += 32) {
        __syncthreads();
#pragma unroll
        for (int i = t; i < 1024; i += 256)
            ((float4*)Wcs)[i] = ((const float4*)W1)[kc * 32 + i];
        __syncthreads();
        const bool fl = FLIP && (kc >= 256);
        const int ab = fl ? (kc - 256) : kc;
#pragma unroll
        for (int k = 0; k < 32; k += 4) {
            float4 a[4], w[4];
#pragma unroll
            for (int i = 0; i < 4; i++) {
                int r = 4 * tr + i;
                if (fl) r ^= 1;
                a[i] = f4_load(Xs + r * 256 + ab + k);
            }
#pragma unroll
            for (int kk = 0; kk < 4; kk++)
                w[kk] = f4_load(Wcs + (k + kk) * 128 + 4 * tc);
            micro_fma(a, w, acc);
        }
    }
    float4 bv = f4_load(b1 + 4 * tc);
    __syncthreads();
#pragma unroll
    for (int i = 0; i < 4; i++) {
        float4 h;
        h.x = fmaxf(acc[i].x + bv.x, 0.f);
        h.y = fmaxf(acc[i].y + bv.y, 0.f);
        h.z = fmaxf(acc[i].z + bv.z, 0.f);
        h.w = fmaxf(acc[i].w + bv.w, 0.f);
        f4_store(Xs + (4 * tr + i) * 256 + 128 + 4 * tc, h);
    }
}

// ---------------- bf16 split helpers ----------------
// RNE versions (weight packing only; one-time cost)
__device__ __forceinline__ unsigned short f2bf(float x) {
    unsigned u = __float_as_uint(x);
    u += 0x7fffu + ((u >> 16) & 1u);           // RNE
    return (unsigned short)(u >> 16);
}
__device__ __forceinline__ float bf2f(unsigned short h) {
    return __uint_as_float(((unsigned)h) << 16);
}
// FAST split (hot path): truncation-based. h = top16(x) (exact residual is
// representable in fp32), l = top16(x - h). Pair error ~2^-17 like RNE split,
// but 4 VALU ops instead of ~12 (conversions were ~36% VALUBusy).
__device__ __forceinline__ void split_bf(float x, unsigned short& h, unsigned short& l) {
    unsigned u = __float_as_uint(x);
    h = (unsigned short)(u >> 16);
    float r = x - __uint_as_float(u & 0xffff0000u);   // exact
    l = (unsigned short)(__float_as_uint(r) >> 16);
}
__device__ __forceinline__ void cvt4(const float4& a, short4v& h, short4v& l) {
    unsigned short h0,h1,h2,h3,l0,l1,l2,l3;
    split_bf(a.x,h0,l0); split_bf(a.y,h1,l1); split_bf(a.z,h2,l2); split_bf(a.w,h3,l3);
    h = (short4v){(short)h0,(short)h1,(short)h2,(short)h3};
    l = (short4v){(short)l0,(short)l1,(short)l2,(short)l3};
}
__device__ __forceinline__ void cvt8(const float4& a, const float4& b, short8v& h, short8v& l) {
    unsigned short h0,h1,h2,h3,h4,h5,h6,h7,l0,l1,l2,l3,l4,l5,l6,l7;
    split_bf(a.x,h0,l0); split_bf(a.y,h1,l1); split_bf(a.z,h2,l2); split_bf(a.w,h3,l3);
    split_bf(b.x,h4,l4); split_bf(b.y,h5,l5); split_bf(b.z,h6,l6); split_bf(b.w,h7,l7);
    h = (short8v){(short)h0,(short)h1,(short)h2,(short)h3,(short)h4,(short)h5,(short)h6,(short)h7};
    l = (short8v){(short)l0,(short)l1,(short)l2,(short)l3,(short)l4,(short)l5,(short)l6,(short)l7};
}

// Plane swizzle: [32][128] bf16, row stride 256 B, XOR bit4..6 by row&7
__device__ __forceinline__ int pswz(int r, int k) { return (r * 256 + k * 2) ^ ((r & 7) << 4); }

// ---------------- weight packing ----------------
__global__ void pack_weights(const float* __restrict__ W, short* __restrict__ out, int K)
{
    int o = blockIdx.x * 256 + threadIdx.x;
    if (o >= 2 * K * 128) return;
    int i = o & 7;
    int g = o >> 3;
    int n  = g & 127;
    int kk = (g >> 7) & 3;
    int p  = (g >> 9) & 1;
    int c  = g >> 10;
    int k  = c * 32 + kk * 8 + i;
    float x = W[k * 128 + n];
    unsigned short h = f2bf(x);
    unsigned short v = p ? f2bf(x - bf2f(h)) : h;
    out[o] = (short)v;
}

// ---------------- setup kernels ----------------
__global__ void fill_kernel(float* __restrict__ L, float* __restrict__ C,
                            const float* __restrict__ lsp, const float* __restrict__ csp)
{
    const float ls = *lsp, cs = *csp;
    const size_t stride = (size_t)gridDim.x * blockDim.x;
    size_t i0 = (size_t)blockIdx.x * blockDim.x + threadIdx.x;
    const size_t nL = (size_t)NL_ * D_ / 4, nC = (size_t)NC_ * D_ / 4;
    float4 lv = make_float4(ls, ls, ls, ls), cv = make_float4(cs, cs, cs, cs);
    for (size_t i = i0; i < nL; i += stride) ((float4*)L)[i] = lv;
    for (size_t i = i0; i < nC; i += stride) ((float4*)C)[i] = cv;
}

__global__ void count_kernel(const int* __restrict__ ci, const int* __restrict__ li,
                             int* __restrict__ ccnt, int* __restrict__ lcnt)
{
    int e = blockIdx.x * 256 + threadIdx.x;
    if (e < NE_) {
        atomicAdd(&ccnt[ci[e]], 1);
        atomicAdd(&lcnt[li[e]], 1);
    }
}

__global__ void scan_block(const int* __restrict__ in, int* __restrict__ out,
                           int* __restrict__ bsum)
{
    __shared__ int sh[256];
    const int t = threadIdx.x;
    const int base = blockIdx.x * 1024 + t * 4;
    int v0 = in[base], v1 = in[base + 1], v2 = in[base + 2], v3 = in[base + 3];
    int s = v0 + v1 + v2 + v3;
    sh[t] = s;
    __syncthreads();
    for (int off = 1; off < 256; off <<= 1) {
        int y = (t >= off) ? sh[t - off] : 0;
        __syncthreads();
        sh[t] += y;
        __syncthreads();
    }
    int excl = sh[t] - s;
    out[base + 0] = excl;
    out[base + 1] = excl + v0;
    out[base + 2] = excl + v0 + v1;
    out[base + 3] = excl + v0 + v1 + v2;
    if (t == 255) bsum[blockIdx.x] = sh[255];
}

__global__ void scan_top(int* __restrict__ bs, int n)
{
    __shared__ int sh[256];
    const int t = threadIdx.x;
    int v = (t < n) ? bs[t] : 0;
    sh[t] = v;
    __syncthreads();
    for (int off = 1; off < 256; off <<= 1) {
        int y = (t >= off) ? sh[t - off] : 0;
        __syncthreads();
        sh[t] += y;
        __syncthreads();
    }
    if (t < n) bs[t] = sh[t] - v;
}

__global__ void scan_add(int* __restrict__ offs, const int* __restrict__ bs,
                         int* __restrict__ cur, int n, int total)
{
    int i = blockIdx.x * 256 + threadIdx.x;
    if (i < n) {
        int v = offs[i] + bs[i >> 10];
        offs[i] = v;
        cur[i] = v;
    }
    if (i == 0) offs[n] = total;
}

__global__ void fill_csr(const int* __restrict__ ci, const int* __restrict__ li,
                         int* __restrict__ ccur, int* __restrict__ lcur,
                         int* __restrict__ cedges, int* __restrict__ ledges)
{
    int e = blockIdx.x * 256 + threadIdx.x;
    if (e < NE_) {
        int c = ci[e], l = li[e];
        int p = atomicAdd(&ccur[c], 1); cedges[p] = l;
        int q = atomicAdd(&lcur[l], 1); ledges[q] = c;
    }
}

// ---------------- fused update kernel (round-8 structure + fast split) --------------
// LDS planes [32][128] bf16:
//   PlaneS_hi @0, PlaneS_lo @8192      (state; never overwritten -> residual source)
//   PlaneM_hi @16384, PlaneM_lo @24576 (messages; reused for H after layer 1)
// Reverted: r9/r11 register preloads (spilled: WRITE_SIZE +170MB) and setprio.
template<bool FLIP>
__global__ __launch_bounds__(256, 5) void update_mfma(
        float* __restrict__ Mat, const float* __restrict__ Src,
        const int* __restrict__ offs, const int* __restrict__ eidx,
        const short* __restrict__ Wp1, const float* __restrict__ b1,
        const short* __restrict__ Wp2, const float* __restrict__ b2,
        const float* __restrict__ scale_p)
{
    __shared__ __align__(16) unsigned char SM[32768];
    unsigned char* sm = SM;
    const int t = threadIdx.x;
    const int base = blockIdx.x * 32;
    const int lane = t & 63, w = t >> 6;
    const int rA = lane & 31;          // A row / D col-in-tile
    const int kg = lane >> 5;          // k-octet group
    const int nB = w * 32 + rA;        // global output col for B frag / bias / D

    // ---- issue state loads first (nt; arrive while gather chain runs)
    float4 sv[4];
#pragma unroll
    for (int j = 0; j < 4; ++j)
        sv[j] = f4_load_nt((const float*)(((const float4*)Mat) + (size_t)base * 32 + t + j * 256));

    // ---- gather messages (longest dependency chain), 2-edge unroll
    float4 a0 = f4_zero(), a1 = f4_zero(), a2 = f4_zero(), a3 = f4_zero();
    const int gr = t >> 3, gs = t & 7;
    {
        const int row = base + gr;
        const int e0 = offs[row], e1 = offs[row + 1];
        int e = e0;
        for (; e + 1 < e1; e += 2) {
            const float* P = Src + (size_t)eidx[e] * 128 + gs * 16;
            const float* Q = Src + (size_t)eidx[e + 1] * 128 + gs * 16;
            float4 p0 = f4_load(P), p1 = f4_load(P + 4), p2 = f4_load(P + 8), p3 = f4_load(P + 12);
            float4 q0 = f4_load(Q), q1 = f4_load(Q + 4), q2 = f4_load(Q + 8), q3 = f4_load(Q + 12);
            a0 = f4_add(a0, p0); a1 = f4_add(a1, p1); a2 = f4_add(a2, p2); a3 = f4_add(a3, p3);
            a0 = f4_add(a0, q0); a1 = f4_add(a1, q1); a2 = f4_add(a2, q2); a3 = f4_add(a3, q3);
        }
        if (e < e1) {
            const float* P = Src + (size_t)eidx[e] * 128 + gs * 16;
            a0 = f4_add(a0, f4_load(P));
            a1 = f4_add(a1, f4_load(P + 4));
            a2 = f4_add(a2, f4_load(P + 8));
            a3 = f4_add(a3, f4_load(P + 12));
        }
    }

    // ---- store state -> PlaneS
#pragma unroll
    for (int j = 0; j < 4; ++j) {
        int i = t + j * 256;
        int r = i >> 5, q = i & 31;
        short4v hv, lv;
        cvt4(sv[j], hv, lv);
        *(short4v*)(sm + pswz(r, 4 * q)) = hv;
        *(short4v*)(sm + 8192 + pswz(r, 4 * q)) = lv;
    }
    // ---- store msgs -> PlaneM
    {
        const float sc = *scale_p;
        a0 = f4_scale(a0, sc); a1 = f4_scale(a1, sc);
        a2 = f4_scale(a2, sc); a3 = f4_scale(a3, sc);
        short8v mh0, ml0, mh1, ml1;
        cvt8(a0, a1, mh0, ml0);
        cvt8(a2, a3, mh1, ml1);
        const int k0 = 16 * gs;
        *(short8v*)(sm + 16384 + pswz(gr, k0))     = mh0;
        *(short8v*)(sm + 16384 + pswz(gr, k0 + 8)) = mh1;
        *(short8v*)(sm + 24576 + pswz(gr, k0))     = ml0;
        *(short8v*)(sm + 24576 + pswz(gr, k0 + 8)) = ml1;
    }
    __syncthreads();   // B1: PlaneS + PlaneM ready

    f32x16 c0, c1;
#pragma unroll
    for (int i = 0; i < 16; ++i) { c0[i] = 0.f; c1[i] = 0.f; }

#define MFMA_STEP(Wp, st, ka, ar, AB) do {                                          \
        short8v ah = *(const short8v*)(sm + (AB) + pswz((ar), (ka)));               \
        short8v al = *(const short8v*)(sm + (AB) + 8192 + pswz((ar), (ka)));        \
        const short* Wc = (Wp) + ((st) >> 1) * 8192;                                \
        const int kk = ((st) & 1) * 2 + kg;                                         \
        short8v bh = *(const short8v*)(Wc + ((size_t)(kk * 128 + nB)) * 8);         \
        short8v bl = *(const short8v*)(Wc + ((size_t)((4 + kk) * 128 + nB)) * 8);   \
        c0 = __builtin_amdgcn_mfma_f32_32x32x16_bf16(ah, bh, c0, 0, 0, 0);          \
        c1 = __builtin_amdgcn_mfma_f32_32x32x16_bf16(ah, bl, c1, 0, 0, 0);          \
        c1 = __builtin_amdgcn_mfma_f32_32x32x16_bf16(al, bh, c1, 0, 0, 0);          \
    } while (0)

    // ---- layer 1: one MFMA run (state + msgs [+ flip])
#pragma unroll 2
    for (int st = 0; st < 8; ++st)
        MFMA_STEP(Wp1, st, st * 16 + kg * 8, rA, 0);           // state cols (PlaneS)
#pragma unroll 2
    for (int st = 8; st < 16; ++st)
        MFMA_STEP(Wp1, st, (st - 8) * 16 + kg * 8, rA, 16384); // msg cols (PlaneM)
    if (FLIP) {
#pragma unroll 2
        for (int st = 16; st < 24; ++st)
            MFMA_STEP(Wp1, st, (st - 16) * 16 + kg * 8, rA ^ 1, 0); // flip: PlaneS, paired row
    }
    __syncthreads();   // B2: all PlaneM (msg) reads done -> safe to overwrite with H

    // ---- H = relu(acc + b1) -> PlaneM (hi/lo)
    {
        const float b = b1[nB];
#pragma unroll
        for (int i = 0; i < 16; ++i) {
            int row = (i & 3) + 8 * (i >> 2) + 4 * kg;
            float h = fmaxf(c0[i] + c1[i] + b, 0.f);
            unsigned short hh, hl;
            split_bf(h, hh, hl);
            *(short*)(sm + 16384 + pswz(row, nB)) = (short)hh;
            *(short*)(sm + 24576 + pswz(row, nB)) = (short)hl;
        }
    }
    __syncthreads();   // B3: H visible

    // ---- residual from PlaneS (hi+lo ~= fp32); hidden under layer-2 MFMA
    float res[16];
#pragma unroll
    for (int i = 0; i < 16; ++i) {
        int row = (i & 3) + 8 * (i >> 2) + 4 * kg;
        unsigned short sh = *(const unsigned short*)(sm + pswz(row, nB));
        unsigned short sl = *(const unsigned short*)(sm + 8192 + pswz(row, nB));
        res[i] = bf2f(sh) + bf2f(sl);
    }

    // ---- layer 2: K=128 from PlaneM (H)
#pragma unroll
    for (int i = 0; i < 16; ++i) { c0[i] = 0.f; c1[i] = 0.f; }
#pragma unroll 2
    for (int st = 0; st < 8; ++st)
        MFMA_STEP(Wp2, st, st * 16 + kg * 8, rA, 16384);
#undef MFMA_STEP

    // ---- epilogue: out = acc + b2 + residual (nt store, write-only)
    {
        const float b = b2[nB];
#pragma unroll
        for (int i = 0; i < 16; ++i) {
            int row = (i & 3) + 8 * (i >> 2) + 4 * kg;
            size_t gi = (size_t)(base + row) * 128 + nB;
            __builtin_nontemporal_store(c0[i] + c1[i] + b + res[i], &Mat[gi]);
        }
    }
}

// ---------------- V scores (fp32 vector path, one small dispatch) ----------------
__global__ __launch_bounds__(256) void v_score(
        float* __restrict__ out, const float* __restrict__ Lmat,
        const float* __restrict__ W1, const float* __restrict__ b1,
        const float* __restrict__ W2, const float* __restrict__ b2)
{
    __shared__ float Xs[32 * 256];
    __shared__ float Wcs[32 * 128];
    const int t = threadIdx.x;
    const int base = blockIdx.x * 32;

#pragma unroll
    for (int i = t; i < 2048; i += 256)
        ((float4*)Xs)[i] = ((const float4*)Lmat)[(size_t)base * 64 + i];

    layer1_to_H<256, false>(Xs, Wcs, W1, b1, t);
    __syncthreads();
    if (t < 32) ((float4*)Wcs)[t] = ((const float4*)W2)[t];
    __syncthreads();

    const int r = t >> 3, s = t & 7;
    float sum = 0.f;
#pragma unroll
    for (int j = 0; j < 16; j++)
        sum += Xs[r * 256 + 128 + s * 16 + j] * Wcs[s * 16 + j];
    sum += __shfl_xor(sum, 1);
    sum += __shfl_xor(sum, 2);
    sum += __shfl_xor(sum, 4);
    if (s == 0) out[base + r] = sum + b2[0];
}

// ---------------- launch ----------------
extern "C" void kernel_launch(void* const* d_in, const int* in_sizes, int n_in,
                              void* d_out, int out_size, void* d_ws, size_t ws_size,
                              hipStream_t stream)
{
    const int*   ci   = (const int*)d_in[2];
    const int*   li   = (const int*)d_in[3];
    const float* Lsc  = (const float*)d_in[4];
    const float* Csc  = (const float*)d_in[5];
    const float* LCsc = (const float*)d_in[6];
    const float* CLsc = (const float*)d_in[7];
    const float* C_W1 = (const float*)d_in[8];
    const float* C_b1 = (const float*)d_in[9];
    const float* C_W2 = (const float*)d_in[10];
    const float* C_b2 = (const float*)d_in[11];
    const float* L_W1 = (const float*)d_in[12];
    const float* L_b1 = (const float*)d_in[13];
    const float* L_W2 = (const float*)d_in[14];
    const float* L_b2 = (const float*)d_in[15];
    const float* V_W1 = (const float*)d_in[16];
    const float* V_b1 = (const float*)d_in[17];
    const float* V_W2 = (const float*)d_in[18];
    const float* V_b2 = (const float*)d_in[19];
    float* out = (float*)d_out;

    // workspace carve
    char* w = (char*)d_ws;
    float* Cmat  = (float*)w; w += (size_t)NC_ * D_ * 4;        // 128 MB
    float* Lmat  = (float*)w; w += (size_t)NL_ * D_ * 4;        //  64 MB
    int* coffs   = (int*)w;   w += (size_t)(NC_ + 1) * 4;
    int* ccur    = (int*)w;   w += (size_t)NC_ * 4;
    int* cedges  = (int*)w;   w += (size_t)NE_ * 4;
    int* loffs   = (int*)w;   w += (size_t)(NL_ + 1) * 4;
    int* lcur    = (int*)w;   w += (size_t)NL_ * 4;
    int* ledges  = (int*)w;   w += (size_t)NE_ * 4;
    int* bsumC   = (int*)w;   w += 256 * 4;
    int* bsumL   = (int*)w;   w += 256 * 4;
    short* WpC1  = (short*)w; w += (size_t)2 * 256 * 128 * 2;   // packed hi/lo planes
    short* WpC2  = (short*)w; w += (size_t)2 * 128 * 128 * 2;
    short* WpL1  = (short*)w; w += (size_t)2 * 384 * 128 * 2;
    short* WpL2  = (short*)w; w += (size_t)2 * 128 * 128 * 2;

    hipMemsetAsync(ccur, 0, (size_t)NC_ * 4, stream);
    hipMemsetAsync(lcur, 0, (size_t)NL_ * 4, stream);

    pack_weights<<<(2 * 256 * 128) / 256, 256, 0, stream>>>(C_W1, WpC1, 256);
    pack_weights<<<(2 * 128 * 128) / 256, 256, 0, stream>>>(C_W2, WpC2, 128);
    pack_weights<<<(2 * 384 * 128) / 256, 256, 0, stream>>>(L_W1, WpL1, 384);
    pack_weights<<<(2 * 128 * 128) / 256, 256, 0, stream>>>(L_W2, WpL2, 128);

    fill_kernel<<<2048, 256, 0, stream>>>(Lmat, Cmat, Lsc, Csc);
    count_kernel<<<NE_ / 256, 256, 0, stream>>>(ci, li, ccur, lcur);

    scan_block<<<NC_ / 1024, 256, 0, stream>>>(ccur, coffs, bsumC);
    scan_top<<<1, 256, 0, stream>>>(bsumC, NC_ / 1024);
    scan_add<<<NC_ / 256, 256, 0, stream>>>(coffs, bsumC, ccur, NC_, NE_);

    scan_block<<<NL_ / 1024, 256, 0, stream>>>(lcur, loffs, bsumL);
    scan_top<<<1, 256, 0, stream>>>(bsumL, NL_ / 1024);
    scan_add<<<NL_ / 256, 256, 0, stream>>>(loffs, bsumL, lcur, NL_, NE_);

    fill_csr<<<NE_ / 256, 256, 0, stream>>>(ci, li, ccur, lcur, cedges, ledges);

    for (int r = 0; r < NROUNDS_; r++) {
        update_mfma<false><<<NC_ / 32, 256, 0, stream>>>(
            Cmat, Lmat, coffs, cedges, WpC1, C_b1, WpC2, C_b2, LCsc);
        update_mfma<true><<<NL_ / 32, 256, 0, stream>>>(
            Lmat, Cmat, loffs, ledges, WpL1, L_b1, WpL2, L_b2, CLsc);
    }
    v_score<<<NV_ / 32, 256, 0, stream>>>(out, Lmat, V_W1, V_b1, V_W2, V_b2);
}

// Round 13
// 2814.645 us; speedup vs baseline: 1.1890x; 1.0127x over previous
//
#include <hip/hip_runtime.h>
#include <cstddef>

#define D_    128
#define NV_   65536
#define NL_   131072
#define NC_   262144
#define NE_   1048576
#define NROUNDS_ 8

typedef __attribute__((ext_vector_type(4)))  short short4v;
typedef __attribute__((ext_vector_type(8)))  short short8v;   // 8 bf16 = 4 VGPRs (MFMA A/B frag)
typedef __attribute__((ext_vector_type(16))) float f32x16;    // MFMA 32x32 C/D frag

// ---------------- fp32 helpers ----------------
__device__ __forceinline__ float4 f4_load(const float* p) { return *(const float4*)p; }
__device__ __forceinline__ void   f4_store(float* p, float4 v) { *(float4*)p = v; }
__device__ __forceinline__ float4 f4_zero() { return make_float4(0.f, 0.f, 0.f, 0.f); }
__device__ __forceinline__ float4 f4_add(float4 a, float4 b) {
    a.x += b.x; a.y += b.y; a.z += b.z; a.w += b.w; return a;
}
__device__ __forceinline__ float4 f4_scale(float4 a, float s) {
    a.x *= s; a.y *= s; a.z *= s; a.w *= s; return a;
}
// Non-temporal float4 LOAD only (state self-read: no need to re-allocate in cache;
// lookup still hits L3 if resident). Stores stay REGULAR: each kernel's output is
// the NEXT kernel's gather table, so it must allocate in L3 (r8's nt store was
// forcing every round's state to HBM and back — ~190 MB/dispatch of gather misses).
__device__ __forceinline__ float4 f4_load_nt(const float* p) {
    float x = __builtin_nontemporal_load(p);
    float y = __builtin_nontemporal_load(p + 1);
    float z = __builtin_nontemporal_load(p + 2);
    float w = __builtin_nontemporal_load(p + 3);
    return make_float4(x, y, z, w);
}

__device__ __forceinline__ void micro_fma(const float4 a[4], const float4 w[4], float4 acc[4]) {
#pragma unroll
    for (int i = 0; i < 4; i++) {
        float4 av = a[i];
        acc[i].x += av.x * w[0].x; acc[i].x += av.y * w[1].x; acc[i].x += av.z * w[2].x; acc[i].x += av.w * w[3].x;
        acc[i].y += av.x * w[0].y; acc[i].y += av.y * w[1].y; acc[i].y += av.z * w[2].y; acc[i].y += av.w * w[3].y;
        acc[i].z += av.x * w[0].z; acc[i].z += av.y * w[1].z; acc[i].z += av.z * w[2].z; acc[i].z += av.w * w[3].z;
        acc[i].w += av.x * w[0].w; acc[i].w += av.y * w[1].w; acc[i].w += av.z * w[2].w; acc[i].w += av.w * w[3].w;
    }
}

template<int KD, bool FLIP>
__device__ __forceinline__ void layer1_to_H(float* Xs, float* Wcs,
        const float* __restrict__ W1, const float* __restrict__ b1, int t)
{
    const int tr = t >> 5, tc = t & 31;
    float4 acc[4];
    acc[0] = acc[1] = acc[2] = acc[3] = f4_zero();
#pragma unroll 1
    for (int kc = 0; kc < KD; kc += 32) {
        __syncthreads();
#pragma unroll
        for (int i = t; i < 1024; i += 256)
            ((float4*)Wcs)[i] = ((const float4*)W1)[kc * 32 + i];
        __syncthreads();
        const bool fl = FLIP && (kc >= 256);
        const int ab = fl ? (kc - 256) : kc;
#pragma unroll
        for (int k = 0; k < 32; k += 4) {
            float4 a[4], w[4];
#pragma unroll
            for (int i = 0; i < 4; i++) {
                int r = 4 * tr + i;
                if (fl) r ^= 1;
                a[i] = f4_load(Xs + r * 256 + ab + k);
            }
#pragma unroll
            for (int kk = 0; kk < 4; kk++)
                w[kk] = f4_load(Wcs + (k + kk) * 128 + 4 * tc);
            micro_fma(a, w, acc);
        }
    }
    float4 bv = f4_load(b1 + 4 * tc);
    __syncthreads();
#pragma unroll
    for (int i = 0; i < 4; i++) {
        float4 h;
        h.x = fmaxf(acc[i].x + bv.x, 0.f);
        h.y = fmaxf(acc[i].y + bv.y, 0.f);
        h.z = fmaxf(acc[i].z + bv.z, 0.f);
        h.w = fmaxf(acc[i].w + bv.w, 0.f);
        f4_store(Xs + (4 * tr + i) * 256 + 128 + 4 * tc, h);
    }
}

// ---------------- bf16 split helpers ----------------
// RNE versions (weight packing only; one-time cost)
__device__ __forceinline__ unsigned short f2bf(float x) {
    unsigned u = __float_as_uint(x);
    u += 0x7fffu + ((u >> 16) & 1u);           // RNE
    return (unsigned short)(u >> 16);
}
__device__ __forceinline__ float bf2f(unsigned short h) {
    return __uint_as_float(((unsigned)h) << 16);
}
// FAST split (hot path): truncation-based. h = top16(x) (exact residual is
// representable in fp32), l = top16(x - h). Pair error ~2^-17 like RNE split,
// but ~4 VALU ops instead of ~12.
__device__ __forceinline__ void split_bf(float x, unsigned short& h, unsigned short& l) {
    unsigned u = __float_as_uint(x);
    h = (unsigned short)(u >> 16);
    float r = x - __uint_as_float(u & 0xffff0000u);   // exact
    l = (unsigned short)(__float_as_uint(r) >> 16);
}
__device__ __forceinline__ void cvt4(const float4& a, short4v& h, short4v& l) {
    unsigned short h0,h1,h2,h3,l0,l1,l2,l3;
    split_bf(a.x,h0,l0); split_bf(a.y,h1,l1); split_bf(a.z,h2,l2); split_bf(a.w,h3,l3);
    h = (short4v){(short)h0,(short)h1,(short)h2,(short)h3};
    l = (short4v){(short)l0,(short)l1,(short)l2,(short)l3};
}
__device__ __forceinline__ void cvt8(const float4& a, const float4& b, short8v& h, short8v& l) {
    unsigned short h0,h1,h2,h3,h4,h5,h6,h7,l0,l1,l2,l3,l4,l5,l6,l7;
    split_bf(a.x,h0,l0); split_bf(a.y,h1,l1); split_bf(a.z,h2,l2); split_bf(a.w,h3,l3);
    split_bf(b.x,h4,l4); split_bf(b.y,h5,l5); split_bf(b.z,h6,l6); split_bf(b.w,h7,l7);
    h = (short8v){(short)h0,(short)h1,(short)h2,(short)h3,(short)h4,(short)h5,(short)h6,(short)h7};
    l = (short8v){(short)l0,(short)l1,(short)l2,(short)l3,(short)l4,(short)l5,(short)l6,(short)l7};
}

// Plane swizzle: [32][128] bf16, row stride 256 B, XOR bit4..6 by row&7
__device__ __forceinline__ int pswz(int r, int k) { return (r * 256 + k * 2) ^ ((r & 7) << 4); }

// ---------------- weight packing ----------------
__global__ void pack_weights(const float* __restrict__ W, short* __restrict__ out, int K)
{
    int o = blockIdx.x * 256 + threadIdx.x;
    if (o >= 2 * K * 128) return;
    int i = o & 7;
    int g = o >> 3;
    int n  = g & 127;
    int kk = (g >> 7) & 3;
    int p  = (g >> 9) & 1;
    int c  = g >> 10;
    int k  = c * 32 + kk * 8 + i;
    float x = W[k * 128 + n];
    unsigned short h = f2bf(x);
    unsigned short v = p ? f2bf(x - bf2f(h)) : h;
    out[o] = (short)v;
}

// ---------------- setup kernels ----------------
__global__ void fill_kernel(float* __restrict__ L, float* __restrict__ C,
                            const float* __restrict__ lsp, const float* __restrict__ csp)
{
    const float ls = *lsp, cs = *csp;
    const size_t stride = (size_t)gridDim.x * blockDim.x;
    size_t i0 = (size_t)blockIdx.x * blockDim.x + threadIdx.x;
    const size_t nL = (size_t)NL_ * D_ / 4, nC = (size_t)NC_ * D_ / 4;
    float4 lv = make_float4(ls, ls, ls, ls), cv = make_float4(cs, cs, cs, cs);
    for (size_t i = i0; i < nL; i += stride) ((float4*)L)[i] = lv;
    for (size_t i = i0; i < nC; i += stride) ((float4*)C)[i] = cv;
}

__global__ void count_kernel(const int* __restrict__ ci, const int* __restrict__ li,
                             int* __restrict__ ccnt, int* __restrict__ lcnt)
{
    int e = blockIdx.x * 256 + threadIdx.x;
    if (e < NE_) {
        atomicAdd(&ccnt[ci[e]], 1);
        atomicAdd(&lcnt[li[e]], 1);
    }
}

__global__ void scan_block(const int* __restrict__ in, int* __restrict__ out,
                           int* __restrict__ bsum)
{
    __shared__ int sh[256];
    const int t = threadIdx.x;
    const int base = blockIdx.x * 1024 + t * 4;
    int v0 = in[base], v1 = in[base + 1], v2 = in[base + 2], v3 = in[base + 3];
    int s = v0 + v1 + v2 + v3;
    sh[t] = s;
    __syncthreads();
    for (int off = 1; off < 256; off <<= 1) {
        int y = (t >= off) ? sh[t - off] : 0;
        __syncthreads();
        sh[t] += y;
        __syncthreads();
    }
    int excl = sh[t] - s;
    out[base + 0] = excl;
    out[base + 1] = excl + v0;
    out[base + 2] = excl + v0 + v1;
    out[base + 3] = excl + v0 + v1 + v2;
    if (t == 255) bsum[blockIdx.x] = sh[255];
}

__global__ void scan_top(int* __restrict__ bs, int n)
{
    __shared__ int sh[256];
    const int t = threadIdx.x;
    int v = (t < n) ? bs[t] : 0;
    sh[t] = v;
    __syncthreads();
    for (int off = 1; off < 256; off <<= 1) {
        int y = (t >= off) ? sh[t - off] : 0;
        __syncthreads();
        sh[t] += y;
        __syncthreads();
    }
    if (t < n) bs[t] = sh[t] - v;
}

__global__ void scan_add(int* __restrict__ offs, const int* __restrict__ bs,
                         int* __restrict__ cur, int n, int total)
{
    int i = blockIdx.x * 256 + threadIdx.x;
    if (i < n) {
        int v = offs[i] + bs[i >> 10];
        offs[i] = v;
        cur[i] = v;
    }
    if (i == 0) offs[n] = total;
}

__global__ void fill_csr(const int* __restrict__ ci, const int* __restrict__ li,
                         int* __restrict__ ccur, int* __restrict__ lcur,
                         int* __restrict__ cedges, int* __restrict__ ledges)
{
    int e = blockIdx.x * 256 + threadIdx.x;
    if (e < NE_) {
        int c = ci[e], l = li[e];
        int p = atomicAdd(&ccur[c], 1); cedges[p] = l;
        int q = atomicAdd(&lcur[l], 1); ledges[q] = c;
    }
}

// ---------------- fused update kernel (round-12 structure, regular epilogue store) --
// LDS planes [32][128] bf16:
//   PlaneS_hi @0, PlaneS_lo @8192      (state; never overwritten -> residual source)
//   PlaneM_hi @16384, PlaneM_lo @24576 (messages; reused for H after layer 1)
template<bool FLIP>
__global__ __launch_bounds__(256, 5) void update_mfma(
        float* __restrict__ Mat, const float* __restrict__ Src,
        const int* __restrict__ offs, const int* __restrict__ eidx,
        const short* __restrict__ Wp1, const float* __restrict__ b1,
        const short* __restrict__ Wp2, const float* __restrict__ b2,
        const float* __restrict__ scale_p)
{
    __shared__ __align__(16) unsigned char SM[32768];
    unsigned char* sm = SM;
    const int t = threadIdx.x;
    const int base = blockIdx.x * 32;
    const int lane = t & 63, w = t >> 6;
    const int rA = lane & 31;          // A row / D col-in-tile
    const int kg = lane >> 5;          // k-octet group
    const int nB = w * 32 + rA;        // global output col for B frag / bias / D

    // ---- issue state loads first (nt read; arrive while gather chain runs)
    float4 sv[4];
#pragma unroll
    for (int j = 0; j < 4; ++j)
        sv[j] = f4_load_nt((const float*)(((const float4*)Mat) + (size_t)base * 32 + t + j * 256));

    // ---- gather messages (longest dependency chain), 2-edge unroll
    float4 a0 = f4_zero(), a1 = f4_zero(), a2 = f4_zero(), a3 = f4_zero();
    const int gr = t >> 3, gs = t & 7;
    {
        const int row = base + gr;
        const int e0 = offs[row], e1 = offs[row + 1];
        int e = e0;
        for (; e + 1 < e1; e += 2) {
            const float* P = Src + (size_t)eidx[e] * 128 + gs * 16;
            const float* Q = Src + (size_t)eidx[e + 1] * 128 + gs * 16;
            float4 p0 = f4_load(P), p1 = f4_load(P + 4), p2 = f4_load(P + 8), p3 = f4_load(P + 12);
            float4 q0 = f4_load(Q), q1 = f4_load(Q + 4), q2 = f4_load(Q + 8), q3 = f4_load(Q + 12);
            a0 = f4_add(a0, p0); a1 = f4_add(a1, p1); a2 = f4_add(a2, p2); a3 = f4_add(a3, p3);
            a0 = f4_add(a0, q0); a1 = f4_add(a1, q1); a2 = f4_add(a2, q2); a3 = f4_add(a3, q3);
        }
        if (e < e1) {
            const float* P = Src + (size_t)eidx[e] * 128 + gs * 16;
            a0 = f4_add(a0, f4_load(P));
            a1 = f4_add(a1, f4_load(P + 4));
            a2 = f4_add(a2, f4_load(P + 8));
            a3 = f4_add(a3, f4_load(P + 12));
        }
    }

    // ---- store state -> PlaneS
#pragma unroll
    for (int j = 0; j < 4; ++j) {
        int i = t + j * 256;
        int r = i >> 5, q = i & 31;
        short4v hv, lv;
        cvt4(sv[j], hv, lv);
        *(short4v*)(sm + pswz(r, 4 * q)) = hv;
        *(short4v*)(sm + 8192 + pswz(r, 4 * q)) = lv;
    }
    // ---- store msgs -> PlaneM
    {
        const float sc = *scale_p;
        a0 = f4_scale(a0, sc); a1 = f4_scale(a1, sc);
        a2 = f4_scale(a2, sc); a3 = f4_scale(a3, sc);
        short8v mh0, ml0, mh1, ml1;
        cvt8(a0, a1, mh0, ml0);
        cvt8(a2, a3, mh1, ml1);
        const int k0 = 16 * gs;
        *(short8v*)(sm + 16384 + pswz(gr, k0))     = mh0;
        *(short8v*)(sm + 16384 + pswz(gr, k0 + 8)) = mh1;
        *(short8v*)(sm + 24576 + pswz(gr, k0))     = ml0;
        *(short8v*)(sm + 24576 + pswz(gr, k0 + 8)) = ml1;
    }
    __syncthreads();   // B1: PlaneS + PlaneM ready

    f32x16 c0, c1;
#pragma unroll
    for (int i = 0; i < 16; ++i) { c0[i] = 0.f; c1[i] = 0.f; }

#define MFMA_STEP(Wp, st, ka, ar, AB) do {                                          \
        short8v ah = *(const short8v*)(sm + (AB) + pswz((ar), (ka)));               \
        short8v al = *(const short8v*)(sm + (AB) + 8192 + pswz((ar), (ka)));        \
        const short* Wc = (Wp) + ((st) >> 1) * 8192;                                \
        const int kk = ((st) & 1) * 2 + kg;                                         \
        short8v bh = *(const short8v*)(Wc + ((size_t)(kk * 128 + nB)) * 8);         \
        short8v bl = *(const short8v*)(Wc + ((size_t)((4 + kk) * 128 + nB)) * 8);   \
        c0 = __builtin_amdgcn_mfma_f32_32x32x16_bf16(ah, bh, c0, 0, 0, 0);          \
        c1 = __builtin_amdgcn_mfma_f32_32x32x16_bf16(ah, bl, c1, 0, 0, 0);          \
        c1 = __builtin_amdgcn_mfma_f32_32x32x16_bf16(al, bh, c1, 0, 0, 0);          \
    } while (0)

    // ---- layer 1: one MFMA run (state + msgs [+ flip])
#pragma unroll 2
    for (int st = 0; st < 8; ++st)
        MFMA_STEP(Wp1, st, st * 16 + kg * 8, rA, 0);           // state cols (PlaneS)
#pragma unroll 2
    for (int st = 8; st < 16; ++st)
        MFMA_STEP(Wp1, st, (st - 8) * 16 + kg * 8, rA, 16384); // msg cols (PlaneM)
    if (FLIP) {
#pragma unroll 2
        for (int st = 16; st < 24; ++st)
            MFMA_STEP(Wp1, st, (st - 16) * 16 + kg * 8, rA ^ 1, 0); // flip: PlaneS, paired row
    }
    __syncthreads();   // B2: all PlaneM (msg) reads done -> safe to overwrite with H

    // ---- H = relu(acc + b1) -> PlaneM (hi/lo)
    {
        const float b = b1[nB];
#pragma unroll
        for (int i = 0; i < 16; ++i) {
            int row = (i & 3) + 8 * (i >> 2) + 4 * kg;
            float h = fmaxf(c0[i] + c1[i] + b, 0.f);
            unsigned short hh, hl;
            split_bf(h, hh, hl);
            *(short*)(sm + 16384 + pswz(row, nB)) = (short)hh;
            *(short*)(sm + 24576 + pswz(row, nB)) = (short)hl;
        }
    }
    __syncthreads();   // B3: H visible

    // ---- residual from PlaneS (hi+lo ~= fp32); hidden under layer-2 MFMA
    float res[16];
#pragma unroll
    for (int i = 0; i < 16; ++i) {
        int row = (i & 3) + 8 * (i >> 2) + 4 * kg;
        unsigned short sh = *(const unsigned short*)(sm + pswz(row, nB));
        unsigned short sl = *(const unsigned short*)(sm + 8192 + pswz(row, nB));
        res[i] = bf2f(sh) + bf2f(sl);
    }

    // ---- layer 2: K=128 from PlaneM (H)
#pragma unroll
    for (int i = 0; i < 16; ++i) { c0[i] = 0.f; c1[i] = 0.f; }
#pragma unroll 2
    for (int st = 0; st < 8; ++st)
        MFMA_STEP(Wp2, st, st * 16 + kg * 8, rA, 16384);
#undef MFMA_STEP

    // ---- epilogue: out = acc + b2 + residual. REGULAR store: this output is the
    //      next kernel's gather table and must be L3-allocated (cf. r8/r12 FETCH).
    {
        const float b = b2[nB];
#pragma unroll
        for (int i = 0; i < 16; ++i) {
            int row = (i & 3) + 8 * (i >> 2) + 4 * kg;
            size_t gi = (size_t)(base + row) * 128 + nB;
            Mat[gi] = c0[i] + c1[i] + b + res[i];
        }
    }
}

// ---------------- V scores (fp32 vector path, one small dispatch) ----------------
__global__ __launch_bounds__(256) void v_score(
        float* __restrict__ out, const float* __restrict__ Lmat,
        const float* __restrict__ W1, const float* __restrict__ b1,
        const float* __restrict__ W2, const float* __restrict__ b2)
{
    __shared__ float Xs[32 * 256];
    __shared__ float Wcs[32 * 128];
    const int t = threadIdx.x;
    const int base = blockIdx.x * 32;

#pragma unroll
    for (int i = t; i < 2048; i += 256)
        ((float4*)Xs)[i] = ((const float4*)Lmat)[(size_t)base * 64 + i];

    layer1_to_H<256, false>(Xs, Wcs, W1, b1, t);
    __syncthreads();
    if (t < 32) ((float4*)Wcs)[t] = ((const float4*)W2)[t];
    __syncthreads();

    const int r = t >> 3, s = t & 7;
    float sum = 0.f;
#pragma unroll
    for (int j = 0; j < 16; j++)
        sum += Xs[r * 256 + 128 + s * 16 + j] * Wcs[s * 16 + j];
    sum += __shfl_xor(sum, 1);
    sum += __shfl_xor(sum, 2);
    sum += __shfl_xor(sum, 4);
    if (s == 0) out[base + r] = sum + b2[0];
}

// ---------------- launch ----------------
extern "C" void kernel_launch(void* const* d_in, const int* in_sizes, int n_in,
                              void* d_out, int out_size, void* d_ws, size_t ws_size,
                              hipStream_t stream)
{
    const int*   ci   = (const int*)d_in[2];
    const int*   li   = (const int*)d_in[3];
    const float* Lsc  = (const float*)d_in[4];
    const float* Csc  = (const float*)d_in[5];
    const float* LCsc = (const float*)d_in[6];
    const float* CLsc = (const float*)d_in[7];
    const float* C_W1 = (const float*)d_in[8];
    const float* C_b1 = (const float*)d_in[9];
    const float* C_W2 = (const float*)d_in[10];
    const float* C_b2 = (const float*)d_in[11];
    const float* L_W1 = (const float*)d_in[12];
    const float* L_b1 = (const float*)d_in[13];
    const float* L_W2 = (const float*)d_in[14];
    const float* L_b2 = (const float*)d_in[15];
    const float* V_W1 = (const float*)d_in[16];
    const float* V_b1 = (const float*)d_in[17];
    const float* V_W2 = (const float*)d_in[18];
    const float* V_b2 = (const float*)d_in[19];
    float* out = (float*)d_out;

    // workspace carve
    char* w = (char*)d_ws;
    float* Cmat  = (float*)w; w += (size_t)NC_ * D_ * 4;        // 128 MB
    float* Lmat  = (float*)w; w += (size_t)NL_ * D_ * 4;        //  64 MB
    int* coffs   = (int*)w;   w += (size_t)(NC_ + 1) * 4;
    int* ccur    = (int*)w;   w += (size_t)NC_ * 4;
    int* cedges  = (int*)w;   w += (size_t)NE_ * 4;
    int* loffs   = (int*)w;   w += (size_t)(NL_ + 1) * 4;
    int* lcur    = (int*)w;   w += (size_t)NL_ * 4;
    int* ledges  = (int*)w;   w += (size_t)NE_ * 4;
    int* bsumC   = (int*)w;   w += 256 * 4;
    int* bsumL   = (int*)w;   w += 256 * 4;
    short* WpC1  = (short*)w; w += (size_t)2 * 256 * 128 * 2;   // packed hi/lo planes
    short* WpC2  = (short*)w; w += (size_t)2 * 128 * 128 * 2;
    short* WpL1  = (short*)w; w += (size_t)2 * 384 * 128 * 2;
    short* WpL2  = (short*)w; w += (size_t)2 * 128 * 128 * 2;

    hipMemsetAsync(ccur, 0, (size_t)NC_ * 4, stream);
    hipMemsetAsync(lcur, 0, (size_t)NL_ * 4, stream);

    pack_weights<<<(2 * 256 * 128) / 256, 256, 0, stream>>>(C_W1, WpC1, 256);
    pack_weights<<<(2 * 128 * 128) / 256, 256, 0, stream>>>(C_W2, WpC2, 128);
    pack_weights<<<(2 * 384 * 128) / 256, 256, 0, stream>>>(L_W1, WpL1, 384);
    pack_weights<<<(2 * 128 * 128) / 256, 256, 0, stream>>>(L_W2, WpL2, 128);

    fill_kernel<<<2048, 256, 0, stream>>>(Lmat, Cmat, Lsc, Csc);
    count_kernel<<<NE_ / 256, 256, 0, stream>>>(ci, li, ccur, lcur);

    scan_block<<<NC_ / 1024, 256, 0, stream>>>(ccur, coffs, bsumC);
    scan_top<<<1, 256, 0, stream>>>(bsumC, NC_ / 1024);
    scan_add<<<NC_ / 256, 256, 0, stream>>>(coffs, bsumC, ccur, NC_, NE_);

    scan_block<<<NL_ / 1024, 256, 0, stream>>>(lcur, loffs, bsumL);
    scan_top<<<1, 256, 0, stream>>>(bsumL, NL_ / 1024);
    scan_add<<<NL_ / 256, 256, 0, stream>>>(loffs, bsumL, lcur, NL_, NE_);

    fill_csr<<<NE_ / 256, 256, 0, stream>>>(ci, li, ccur, lcur, cedges, ledges);

    for (int r = 0; r < NROUNDS_; r++) {
        update_mfma<false><<<NC_ / 32, 256, 0, stream>>>(
            Cmat, Lmat, coffs, cedges, WpC1, C_b1, WpC2, C_b2, LCsc);
        update_mfma<true><<<NL_ / 32, 256, 0, stream>>>(
            Lmat, Cmat, loffs, ledges, WpL1, L_b1, WpL2, L_b2, CLsc);
    }
    v_score<<<NV_ / 32, 256, 0, stream>>>(out, Lmat, V_W1, V_b1, V_W2, V_b2);
}